// Round 4
// baseline (256.087 us; speedup 1.0000x reference)
//
#include <hip/hip_runtime.h>
#include <hip/hip_bf16.h>
#include <stdint.h>

#define TN 4096
#define TD 2048
#define TMARGIN 0.3f
#define BK 32
#define NT (TD / BK)   // 64 K-tiles

typedef __bf16 bf16x8 __attribute__((ext_vector_type(8)));
typedef float f32x4 __attribute__((ext_vector_type(4)));

// ---------------------------------------------------------------------------
// Kernel 1: per-row prep — fp32 row norm, bf16 hi/lo split, init ap/an.
// ---------------------------------------------------------------------------
__global__ __launch_bounds__(256) void prep_kernel(
    const float* __restrict__ X,
    __bf16* __restrict__ H, __bf16* __restrict__ L,
    float* __restrict__ sq, float* __restrict__ ap, unsigned* __restrict__ an_bits)
{
    const int r = blockIdx.x;
    const int t = threadIdx.x;
    const float* xr = X + (size_t)r * TD;

    float4 v0 = ((const float4*)xr)[t * 2 + 0];
    float4 v1 = ((const float4*)xr)[t * 2 + 1];
    float xs[8] = {v0.x, v0.y, v0.z, v0.w, v1.x, v1.y, v1.z, v1.w};

    bf16x8 hv, lv;
    float s = 0.f;
#pragma unroll
    for (int i = 0; i < 8; ++i) {
        float x = xs[i];
        s += x * x;
        __bf16 h = (__bf16)x;          // RNE
        float res = x - (float)h;      // exact
        hv[i] = h;
        lv[i] = (__bf16)res;
    }
    ((bf16x8*)(H + (size_t)r * TD))[t] = hv;
    ((bf16x8*)(L + (size_t)r * TD))[t] = lv;

#pragma unroll
    for (int off = 32; off; off >>= 1) s += __shfl_down(s, off);
    __shared__ float red[4];
    if ((t & 63) == 0) red[t >> 6] = s;
    __syncthreads();
    if (t == 0) {
        sq[r] = red[0] + red[1] + red[2] + red[3];
        ap[r] = 0.0f;                   // diagonal positive has dist 0
        an_bits[r] = 0x7f800000u;       // +inf
    }
}

// ---------------------------------------------------------------------------
// Kernel 2: 256x256 tile, 8 waves, 3-pass split-GEMM on a faithful 6-phase
// m201-style schedule: 16 independent MFMAs per phase, 1 stage-issue/phase,
// counted vmcnt placed >=1 barrier before consumers, 2 barriers/phase,
// setprio around MFMA clusters, both-sides XOR swizzle.
// ---------------------------------------------------------------------------
__device__ __forceinline__ void gload_lds16(const void* g, void* l) {
    __builtin_amdgcn_global_load_lds(
        (const __attribute__((address_space(1))) uint32_t*)g,
        (__attribute__((address_space(3))) uint32_t*)l, 16, 0, 0);
}

#define VMCNT(N) asm volatile("s_waitcnt vmcnt(" #N ")" ::: "memory")
#define LGKM0()  asm volatile("s_waitcnt lgkmcnt(0)" ::: "memory")
#define BAR()    __builtin_amdgcn_s_barrier()

__global__ __launch_bounds__(512, 1) void tile_kernel(
    const __bf16* __restrict__ H, const __bf16* __restrict__ L,
    const float* __restrict__ sq, const int* __restrict__ tg,
    unsigned* __restrict__ ap_bits, unsigned* __restrict__ an_bits)
{
    // 2 dbuf x {0=Ha, 1=La, 2=Hb, 3=Lb} x 256 rows x 32 cols bf16 = 128 KiB
    __shared__ __bf16 lds[2][4][256 * BK];

    const int bi = blockIdx.y, bj = blockIdx.x;
    const int brow = bi * 256, bcol = bj * 256;
    const int tid  = threadIdx.x;
    const int lane = tid & 63;
    const int wave = tid >> 6;
    const int wr = wave >> 2;            // 0..1  (M half: rows wr*128..+128)
    const int wc = wave & 3;             // 0..3  (N quarter: cols wc*64..+64)
    const int lr = lane & 15;
    const int lk = lane >> 4;            // 0..3

    // physical slot for frag ds_reads (involutive XOR swizzle; bank-uniform)
    const int qs = lk ^ ((lr ^ (lr >> 2)) & 3);

    // staging: thread covers rows srow and srow+128 of a unit
    const int srow  = tid >> 2;                      // 0..127
    const int sslot = tid & 3;                       // physical 16B slot
    const int rsw   = (srow ^ (srow >> 2)) & 3;      // swz(srow)==swz(srow+128)
    const int scol0 = (sslot ^ rsw) * 8;             // logical col fetched

    f32x4 acc[8][4];
#pragma unroll
    for (int m = 0; m < 8; ++m)
#pragma unroll
        for (int n = 0; n < 4; ++n)
            acc[m][n] = (f32x4){0.f, 0.f, 0.f, 0.f};

    auto stage = [&](const __bf16* __restrict__ src, int rowbase, int d, int u, int k0) {
        const __bf16* g0 = src + (size_t)(rowbase + srow) * TD + (k0 + scol0);
        const __bf16* g1 = src + (size_t)(rowbase + srow + 128) * TD + (k0 + scol0);
        gload_lds16(g0, &lds[d][u][(size_t)tid * 8]);
        gload_lds16(g1, &lds[d][u][(size_t)(tid + 512) * 8]);
    };

    bf16x8 ah[8], bh[4], al[4], bl[4];

    auto readA4 = [&](int d, int u, int mh, bf16x8* dst) {
#pragma unroll
        for (int m = 0; m < 4; ++m) {
            int off = (wr * 128 + mh * 64 + m * 16 + lr) * BK + qs * 8;
            dst[m] = *(const bf16x8*)&lds[d][u][off];
        }
    };
    auto readB4 = [&](int d, int u, bf16x8* dst) {
#pragma unroll
        for (int n = 0; n < 4; ++n) {
            int off = (wc * 64 + n * 16 + lr) * BK + qs * 8;
            dst[n] = *(const bf16x8*)&lds[d][u][off];
        }
    };
    auto mma16 = [&](const bf16x8* a4, const bf16x8* b4, int mbase) {
        __builtin_amdgcn_s_setprio(1);
#pragma unroll
        for (int m = 0; m < 4; ++m)
#pragma unroll
            for (int n = 0; n < 4; ++n)
                acc[mbase + m][n] = __builtin_amdgcn_mfma_f32_16x16x32_bf16(
                    a4[m], b4[n], acc[mbase + m][n], 0, 0, 0);
        __builtin_amdgcn_s_setprio(0);
    };

    // Prologue: stage tile0 fully, drain (one-time), barrier.
    stage(H, brow, 0, 0, 0);   // Ha(0)
    stage(H, bcol, 0, 2, 0);   // Hb(0)
    stage(L, bcol, 0, 3, 0);   // Lb(0)
    stage(L, brow, 0, 1, 0);   // La(0)
    VMCNT(0);
    BAR();

    for (int t = 0; t < NT; ++t) {
        const int d = t & 1, dn = d ^ 1;
        const int k1 = ((t + 1 < NT) ? t + 1 : NT - 1) * BK;

        // p0 (hh,mh0): reads Ha,Hb(t) — drained at (t-1).p5's vmcnt(4)+BAR.
        readA4(d, 0, 0, ah);
        readB4(d, 2, bh);
        stage(H, brow, dn, 0, k1);          // issue Ha'
        BAR(); LGKM0();
        mma16(ah, bh, 0);
        BAR();

        // p1 (hh,mh1)
        readA4(d, 0, 1, ah + 4);
        stage(H, bcol, dn, 2, k1);          // issue Hb'
        VMCNT(6);                           // drain Lb(t)   [queue: Lb,La,Ha',Hb']
        BAR(); LGKM0();
        mma16(ah + 4, bh, 4);
        BAR();

        // p2 (hl,mh0): reads Lb(t) — drained p1.
        readB4(d, 3, bl);
        stage(L, bcol, dn, 3, k1);          // issue Lb'
        BAR(); LGKM0();
        mma16(ah, bl, 0);
        BAR();

        // p3 (hl,mh1): no reads.
        stage(L, brow, dn, 1, k1);          // issue La'
        VMCNT(8);                           // drain La(t)   [queue: La,Ha',Hb',Lb',La']
        BAR();
        mma16(ah + 4, bl, 4);
        BAR();

        // p4 (lh,mh0): reads La(t) — drained p3.
        readA4(d, 1, 0, al);
        BAR(); LGKM0();
        mma16(al, bh, 0);
        BAR();

        // p5 (lh,mh1)
        readA4(d, 1, 1, al);
        VMCNT(4);                           // drain Ha',Hb' [queue: Ha',Hb',Lb',La']
        BAR(); LGKM0();
        mma16(al, bh, 4);
        BAR();
    }

    // Epilogue: dist + hard mining. C/D layout: col=lane&15, row=lk*4+reg.
    float sqj[4]; int tj[4];
#pragma unroll
    for (int n = 0; n < 4; ++n) {
        int j = bcol + wc * 64 + n * 16 + lr;
        sqj[n] = sq[j];
        tj[n]  = tg[j];
    }
#pragma unroll
    for (int m = 0; m < 8; ++m) {
#pragma unroll
        for (int reg = 0; reg < 4; ++reg) {
            int i = brow + wr * 128 + m * 16 + lk * 4 + reg;
            float sqi = sq[i];
            int   ti  = tg[i];
            float pmax = -1.0f;
            float pmin = __uint_as_float(0x7f800000u);
#pragma unroll
            for (int n = 0; n < 4; ++n) {
                float d2   = sqi + sqj[n] - 2.0f * acc[m][n][reg];
                float dist = sqrtf(fmaxf(d2, 1e-12f));
                if (ti == tj[n]) pmax = fmaxf(pmax, dist);
                else             pmin = fminf(pmin, dist);
            }
#pragma unroll
            for (int off = 1; off < 16; off <<= 1) {
                pmax = fmaxf(pmax, __shfl_xor(pmax, off));
                pmin = fminf(pmin, __shfl_xor(pmin, off));
            }
            if (lr == 0) {
                if (pmax >= 0.0f) atomicMax(&ap_bits[i], __float_as_uint(pmax));
                atomicMin(&an_bits[i], __float_as_uint(pmin));
            }
        }
    }
}

// ---------------------------------------------------------------------------
// Kernel 3: loss = mean(relu(ap - an + margin)), prec = mean(an > ap).
// ---------------------------------------------------------------------------
__global__ __launch_bounds__(256) void finalize_kernel(
    const float* __restrict__ ap, const float* __restrict__ an, float* __restrict__ out)
{
    const int t = threadIdx.x;
    float ls = 0.f, ps = 0.f;
    for (int i = t; i < TN; i += 256) {
        float a = ap[i], b = an[i];
        ls += fmaxf(a - b + TMARGIN, 0.f);
        ps += (b > a) ? 1.f : 0.f;
    }
#pragma unroll
    for (int off = 32; off; off >>= 1) {
        ls += __shfl_down(ls, off);
        ps += __shfl_down(ps, off);
    }
    __shared__ float r0[4], r1[4];
    if ((t & 63) == 0) { r0[t >> 6] = ls; r1[t >> 6] = ps; }
    __syncthreads();
    if (t == 0) {
        out[0] = (r0[0] + r0[1] + r0[2] + r0[3]) / (float)TN;
        out[1] = (r1[0] + r1[1] + r1[2] + r1[3]) / (float)TN;
    }
}

// ---------------------------------------------------------------------------
extern "C" void kernel_launch(void* const* d_in, const int* in_sizes, int n_in,
                              void* d_out, int out_size, void* d_ws, size_t ws_size,
                              hipStream_t stream)
{
    const float* X  = (const float*)d_in[0];
    const int*   tg = (const int*)d_in[1];
    float* out = (float*)d_out;

    char* ws = (char*)d_ws;
    __bf16* Hp = (__bf16*)ws;                                   // 16 MB
    __bf16* Lp = (__bf16*)(ws + (size_t)TN * TD * 2);           // 16 MB
    float*  sq = (float*) (ws + (size_t)TN * TD * 4);           // 16 KB
    float*  ap = sq + TN;
    float*  an = ap + TN;

    prep_kernel<<<TN, 256, 0, stream>>>(X, Hp, Lp, sq, ap, (unsigned*)an);

    dim3 grid(4096 / 256, 4096 / 256);   // 16 x 16 = 256 blocks
    tile_kernel<<<grid, 512, 0, stream>>>(Hp, Lp, sq, tg,
                                          (unsigned*)ap, (unsigned*)an);

    finalize_kernel<<<1, 256, 0, stream>>>(ap, an, out);
}